// Round 10
// baseline (358.885 us; speedup 1.0000x reference)
//
#include <hip/hip_runtime.h>
#include <math.h>

#define NPTS 4096
#define EPSC 1e-5f
#define F2C (2.0f*1.44269504088896340736f)

#if __has_builtin(__builtin_amdgcn_exp2f)
#define FEXP2 __builtin_amdgcn_exp2f
#else
#define FEXP2(x) __expf((x)*0.6931471805599453f)
#endif

#define IDX(i,j) ((i)*((i)+1)/2 + (j))   // packed lower-tri, i>=j

// one thread = one pc1 row; one block = (sample, 256-row block, 256-col chunk).
// pc2 chunk staged in LDS; ONLINE softmax (single pass, deferred per-wave rescale).
// LAST block per (sample,row-block) (atomic counter) merges the 16 chunk partials
// in-kernel -> rowdat. No separate merge kernel, no extra boundary.
__global__ void __launch_bounds__(256) k_soft(const float* __restrict__ pc1,
                                              const float* __restrict__ pc2,
                                              float* __restrict__ partM,
                                              float4* __restrict__ partV,
                                              float4* __restrict__ rowdat,
                                              unsigned int* __restrict__ ctr){
  constexpr int CHN = 256, NC = 16;
  int bid = blockIdx.x;                          // 2048 blocks
  int chunk = bid & (NC-1), rb = (bid/NC) & 15, b = bid/(NC*16);

  __shared__ float4 sp[CHN];                     // 4KB
  {
    const float* p2 = pc2 + (size_t)b*4*NPTS + chunk*CHN;
    for (int m = threadIdx.x; m < CHN; m += 256){
      float x = p2[m], y = p2[m+NPTS], z = p2[m+2*NPTS];
      sp[m] = make_float4(x, y, z, x*x + y*y + z*z);
    }
  }
  __syncthreads();

  int n = rb*256 + threadIdx.x;
  const float* p1 = pc1 + (size_t)b*4*NPTS + n;
  float x1 = p1[0], y1 = p1[NPTS], z1 = p1[2*NPTS];
  float q1 = x1*x1 + y1*y1 + z1*z1;
  float mx = -2.f*x1, my = -2.f*y1, mz = -2.f*z1;

  float4 c0 = sp[0];
  float d0 = fmaf(mx,c0.x, fmaf(my,c0.y, fmaf(mz,c0.z, c0.w + q1)));
  float m_ = F2C * __builtin_amdgcn_rcpf(fmaxf(d0, EPSC));   // running max (log2 units)
  float L = 1.f, Ax = c0.x, Ay = c0.y, Az = c0.z;

  #pragma unroll 8
  for (int mm=1; mm<CHN; ++mm){
    float4 c = sp[mm];
    float d = fmaf(mx,c.x, fmaf(my,c.y, fmaf(mz,c.z, c.w + q1)));
    float dinv = __builtin_amdgcn_rcpf(fmaxf(d, EPSC));
    float t = fmaf(F2C, dinv, -m_);              // s - m
    if (__any(t > 0.f)){                         // wave-uniform rescale (rare)
      float tp = fmaxf(t, 0.f);
      float sc = FEXP2(-tp);
      L *= sc; Ax *= sc; Ay *= sc; Az *= sc;
      m_ += tp;
      t = fminf(t, 0.f);                         // s - m_new
    }
    float pe = FEXP2(t);
    L += pe;
    Ax = fmaf(pe,c.x,Ax); Ay = fmaf(pe,c.y,Ay); Az = fmaf(pe,c.z,Az);
  }
  size_t base = (size_t)(b*NC)*NPTS + n;         // + c*NPTS per chunk
  partM[base + (size_t)chunk*NPTS] = m_;
  partV[base + (size_t)chunk*NPTS] = make_float4(L, Ax, Ay, Az);

  // ---- last-block merge (device-scope release/acquire) ----
  __threadfence();                               // release this block's partials
  __syncthreads();
  __shared__ int lastBlk;
  if (threadIdx.x==0){
    unsigned int old = atomicAdd(&ctr[b*16+rb], 1u);
    lastBlk = (old == NC-1);
  }
  __syncthreads();
  if (!lastBlk) return;
  __threadfence();                               // acquire all 16 partials

  float mc[NC];
  #pragma unroll
  for (int c=0;c<NC;c++) mc[c] = partM[base + (size_t)c*NPTS];
  float M = mc[0];
  #pragma unroll
  for (int c=1;c<NC;c++) M = fmaxf(M, mc[c]);
  float Lm=0.f, Axm=0.f, Aym=0.f, Azm=0.f;
  #pragma unroll
  for (int c=0;c<NC;c++){
    float4 v = partV[base + (size_t)c*NPTS];
    float w = FEXP2(mc[c]-M);
    Lm  = fmaf(w, v.x, Lm);
    Axm = fmaf(w, v.y, Axm);
    Aym = fmaf(w, v.z, Aym);
    Azm = fmaf(w, v.w, Azm);
  }
  float inv = 1.f/Lm;
  float px=Axm*inv, py=Aym*inv, pz=Azm*inv;      // x1,y1,z1 still live in regs
  float dx=x1-px, dy=y1-py, dz=z1-pz;
  float dd=sqrtf(dx*dx+dy*dy+dz*dz);
  rowdat[(size_t)b*NPTS + n] = make_float4(px,py,pz,dd);
}

__device__ __forceinline__ void stats_from_tot(const float* stot, float* sst){
  const float Nf = 4096.f, Nm1 = 4095.f;
  #pragma unroll
  for (int j=0;j<3;j++){
    float m  = stot[j]/Nf;
    float v  = (stot[3+j]-Nf*m*m)/Nm1;             // ddof=1
    sst[j]=m; sst[3+j]=sqrtf(fmaxf(v,0.f));
    float m2 = stot[6+j]/Nf;
    float v2 = (stot[9+j]-Nf*m2*m2)/Nm1;
    sst[6+j]=m2; sst[9+j]=sqrtf(fmaxf(v2,0.f));
  }
  sst[12]=stot[12]/Nf;
}

__device__ __forceinline__ float elemA(const float* S, int i, int k){
  int bi=i>>2, bj=k>>2;
  int ii=i&3, jj=k&3;
  int lo = ii<jj?ii:jj, hi = ii<jj?jj:ii;
  int pe = 4*lo - ((lo*(lo-1))>>1) + (hi-lo);        // sym 4x4 -> 10 idx
  int w;
  if (bi==bj) w = (bi==2)?30:0;
  else {
    int blo = bi<bj?bi:bj, bhi = bi<bj?bj:bi;
    if (blo==0 && bhi==1) return 0.f;                // A01 block is zero
    w = (blo==0)?10:20;                              // (0,2)->wB, (1,2)->wC
  }
  return S[w+pe];
}

// 8 blocks x 1024 thr: pass1 13-sums -> stats -> pass2 masked M^T M 40-sums ->
// wave 0 register Cholesky inverse-power eigensolve + compose.
__global__ void __launch_bounds__(1024) k_fin(const float* __restrict__ pc1,
                                              const float4* __restrict__ rowdat,
                                              float* __restrict__ out){
  int b = blockIdx.x, t = threadIdx.x;
  int lane = t & 63, wv = t >> 6;                    // 16 waves

  __shared__ float red13[16][13];
  __shared__ float stot[13];
  __shared__ float sst[13];
  __shared__ float red40[16][40];
  __shared__ float SS[40];

  // ---- pass 1: 13 stats sums ----
  float acc13[13];
  #pragma unroll
  for (int k=0;k<13;k++) acc13[k]=0.f;
  #pragma unroll
  for (int i=0;i<4;i++){
    int n = i*1024 + t;
    const float* p1 = pc1 + (size_t)b*4*NPTS + n;
    float x1=p1[0], y1=p1[NPTS], z1=p1[2*NPTS];
    float4 rd = rowdat[(size_t)b*NPTS + n];
    acc13[0]+=x1;      acc13[1]+=y1;      acc13[2]+=z1;
    acc13[3]+=x1*x1;   acc13[4]+=y1*y1;   acc13[5]+=z1*z1;
    acc13[6]+=rd.x;    acc13[7]+=rd.y;    acc13[8]+=rd.z;
    acc13[9]+=rd.x*rd.x; acc13[10]+=rd.y*rd.y; acc13[11]+=rd.z*rd.z;
    acc13[12]+=rd.w;
  }
  #pragma unroll
  for (int k=0;k<13;k++){
    float v = acc13[k];
    v += __shfl_xor(v,32); v += __shfl_xor(v,16); v += __shfl_xor(v,8);
    v += __shfl_xor(v,4);  v += __shfl_xor(v,2);  v += __shfl_xor(v,1);
    if (lane==0) red13[wv][k]=v;
  }
  __syncthreads();
  if (t<13){
    float s=0.f;
    #pragma unroll
    for (int w=0;w<16;w++) s += red13[w][t];
    stot[t]=s;
  }
  __syncthreads();
  if (t==0) stats_from_tot(stot, sst);
  __syncthreads();

  // ---- pass 2: masked M^T M 40-sums ----
  float i1x=1.f/sst[3], i1y=1.f/sst[4], i1z=1.f/sst[5];
  float t1x=-sst[0]/sst[3], t1y=-sst[1]/sst[4], t1z=-sst[2]/sst[5];
  float i2x=1.f/sst[9], i2y=1.f/sst[10], i2z=1.f/sst[11];
  float t2x=-sst[6]/sst[9], t2y=-sst[7]/sst[10], t2z=-sst[8]/sst[11];
  float meanD=sst[12];

  float acc[40];
  #pragma unroll
  for (int k=0;k<40;k++) acc[k]=0.f;
  #pragma unroll
  for (int i=0;i<4;i++){
    int n = i*1024 + t;
    const float* p1 = pc1 + (size_t)b*4*NPTS + n;
    float X1=fmaf(p1[0],i1x,t1x), Y1=fmaf(p1[NPTS],i1y,t1y), Z1=fmaf(p1[2*NPTS],i1z,t1z);
    float4 rd = rowdat[(size_t)b*NPTS + n];
    float X2=fmaf(rd.x,i2x,t2x);
    float Y2=fmaf(rd.y,i2y,t2y);
    float Z2=fmaf(rd.z,i2z,t2z);
    // sigmoid((dist-mean-EPS)*-1e10) > 0.5  <=>  (dist-mean)-EPS < 0
    float zthr = (rd.w - meanD) - EPSC;
    float msk = (zthr < 0.f) ? 1.f : 0.f;
    float tz = msk*Z2;
    float wA = tz*Z2, wB = -tz*X2, wC = -tz*Y2;
    float wD = msk*fmaf(X2,X2,Y2*Y2);
    float ee[10]={X1*X1, X1*Y1, X1*Z1, X1, Y1*Y1, Y1*Z1, Y1, Z1*Z1, Z1, 1.f};
    #pragma unroll
    for (int j=0;j<10;j++){
      acc[j]    = fmaf(wA,ee[j],acc[j]);
      acc[10+j] = fmaf(wB,ee[j],acc[10+j]);
      acc[20+j] = fmaf(wC,ee[j],acc[20+j]);
      acc[30+j] = fmaf(wD,ee[j],acc[30+j]);
    }
  }
  #pragma unroll
  for (int k=0;k<40;k++){
    float v=acc[k];
    v+=__shfl_xor(v,32); v+=__shfl_xor(v,16); v+=__shfl_xor(v,8);
    v+=__shfl_xor(v,4);  v+=__shfl_xor(v,2);  v+=__shfl_xor(v,1);
    if(lane==0) red40[wv][k]=v;
  }
  __syncthreads();
  if (t<40){
    float s=0.f;
    #pragma unroll
    for (int w=0;w<16;w++) s += red40[w][t];
    SS[t]=s;
  }
  __syncthreads();

  // ---- phase C: wave 0 eigensolve + compose ----
  if (t<64){
    float a[78];
    #pragma unroll
    for (int i=0;i<12;i++)
      #pragma unroll
      for (int j=0;j<=i;j++)
        a[IDX(i,j)] = elemA(SS,i,j);
    {
      float tr=0.f;
      #pragma unroll
      for (int i=0;i<12;i++) tr += a[IDX(i,i)];
      float eps = 1e-5f * tr * (1.f/12.f);           // uniform shift: eigvecs unchanged
      #pragma unroll
      for (int i=0;i<12;i++) a[IDX(i,i)] += eps;
    }
    #pragma unroll
    for (int j=0;j<12;j++){
      float s = a[IDX(j,j)];
      #pragma unroll
      for (int k=0;k<j;k++) s = fmaf(-a[IDX(j,k)], a[IDX(j,k)], s);
      float d = sqrtf(fmaxf(s, 1e-30f));
      a[IDX(j,j)] = d;
      float dinv = __builtin_amdgcn_rcpf(d);
      #pragma unroll
      for (int i=j+1;i<12;i++){
        float s2 = a[IDX(i,j)];
        #pragma unroll
        for (int k=0;k<j;k++) s2 = fmaf(-a[IDX(i,k)], a[IDX(j,k)], s2);
        a[IDX(i,j)] = s2 * dinv;
      }
    }
    // lane j: solve (A+eps I) x = e_j -> column j of B (lanes >=12 stay exactly 0)
    float y[12], Brow[12];
    #pragma unroll
    for (int i=0;i<12;i++){
      float s = (i==t) ? 1.f : 0.f;
      #pragma unroll
      for (int k=0;k<i;k++) s = fmaf(-a[IDX(i,k)], y[k], s);
      y[i] = s * __builtin_amdgcn_rcpf(a[IDX(i,i)]);
    }
    #pragma unroll
    for (int i=11;i>=0;i--){
      float s = y[i];
      #pragma unroll
      for (int k=11;k>i;k--) s = fmaf(-a[IDX(k,i)], Brow[k], s);
      Brow[i] = s * __builtin_amdgcn_rcpf(a[IDX(i,i)]);
    }
    {
      float mxv = 0.f;
      #pragma unroll
      for (int i=0;i<12;i++) mxv = fmaxf(mxv, fabsf(Brow[i]));
      mxv = fmaxf(mxv, __shfl_xor(mxv,1)); mxv = fmaxf(mxv, __shfl_xor(mxv,2));
      mxv = fmaxf(mxv, __shfl_xor(mxv,4)); mxv = fmaxf(mxv, __shfl_xor(mxv,8));
      float sc = __builtin_amdgcn_rcpf(mxv);
      #pragma unroll
      for (int i=0;i<12;i++) Brow[i] *= sc;
    }
    #pragma unroll
    for (int rep=0; rep<2; ++rep){                   // B -> B^2 -> B^4
      float nr[12];
      #pragma unroll
      for (int i=0;i<12;i++) nr[i]=0.f;
      #pragma unroll
      for (int k=0;k<12;k++){
        float bjk = Brow[k];
        #pragma unroll
        for (int m2=0;m2<12;m2++){
          float bkm = __shfl(Brow[m2], k);
          nr[m2] = fmaf(bjk, bkm, nr[m2]);
        }
      }
      float mxv = 0.f;
      #pragma unroll
      for (int i=0;i<12;i++) mxv = fmaxf(mxv, fabsf(nr[i]));
      mxv = fmaxf(mxv, __shfl_xor(mxv,1)); mxv = fmaxf(mxv, __shfl_xor(mxv,2));
      mxv = fmaxf(mxv, __shfl_xor(mxv,4)); mxv = fmaxf(mxv, __shfl_xor(mxv,8));
      float sc = __builtin_amdgcn_rcpf(mxv);
      #pragma unroll
      for (int i=0;i<12;i++) Brow[i] = nr[i]*sc;
    }
    float v = 0.f;
    #pragma unroll
    for (int i=0;i<12;i++) v += Brow[i];
    #pragma unroll
    for (int it=0; it<14; ++it){
      float w = 0.f;
      #pragma unroll
      for (int k=0;k<12;k++) w = fmaf(Brow[k], __shfl(v,k), w);
      float nn = w*w;
      nn += __shfl_xor(nn,1); nn += __shfl_xor(nn,2);
      nn += __shfl_xor(nn,4); nn += __shfl_xor(nn,8);
      v = w * rsqrtf(nn);
    }
    float pvf[12];
    #pragma unroll
    for (int i=0;i<12;i++) pvf[i] = __shfl(v, i);

    if (t==0){
      double pv[12];
      #pragma unroll
      for (int i=0;i<12;i++) pv[i]=(double)pvf[i];
      if (pv[10]<0.0){
        #pragma unroll
        for (int i=0;i<12;i++) pv[i]=-pv[i];
      }
      double nrm = sqrt(pv[8]*pv[8]+pv[9]*pv[9]+pv[10]*pv[10]);
      #pragma unroll
      for (int i=0;i<12;i++) pv[i]/=nrm;
      double m1[3]={sst[0],sst[1],sst[2]}, sd1[3]={sst[3],sst[4],sst[5]};
      double m2[3]={sst[6],sst[7],sst[8]}, sd2[3]={sst[9],sst[10],sst[11]};
      double Td[3][4]={{pv[0],pv[1],pv[2],pv[3]},
                       {pv[4],pv[5],pv[6],pv[7]},
                       {pv[8],pv[9],pv[10],pv[11]}};
      double F[3][4];
      for (int i=0;i<3;i++){
        double b3 = Td[i][3];
        for (int j=0;j<3;j++){
          F[i][j] = sd2[i]*(Td[i][j]/sd1[j]);        // inv(T2) @ Tdlt @ T1
          b3 += Td[i][j]*(-m1[j]/sd1[j]);
        }
        F[i][3] = sd2[i]*b3 + m2[i];
      }
      double zx=F[0][2],zy=F[1][2],zz2=F[2][2];
      double zn=sqrt(zx*zx+zy*zy+zz2*zz2);
      zx/=zn; zy/=zn; zz2/=zn;
      double yx=F[0][1],yy=F[1][1],yz=F[2][1];
      double xx=yy*zz2-yz*zy, xy=yz*zx-yx*zz2, xz=yx*zy-yy*zx;
      double xn=sqrt(xx*xx+xy*xy+xz*xz);
      xx/=xn; xy/=xn; xz/=xn;
      double y2x=zy*xz-zz2*xy, y2y=zz2*xx-zx*xz, y2z=zx*xy-zy*xx;
      double R00=xx,R01=y2x,R02=zx;
      double R10=xy,R11=y2y,R12=zy;
      double R20=xz,R21=y2z,R22=zz2;
      float* oT = out + b*16;
      oT[0]=(float)R00; oT[1]=(float)R01; oT[2]=(float)R02; oT[3]=(float)F[0][3];
      oT[4]=(float)R10; oT[5]=(float)R11; oT[6]=(float)R12; oT[7]=(float)F[1][3];
      oT[8]=(float)R20; oT[9]=(float)R21; oT[10]=(float)R22; oT[11]=(float)F[2][3];
      oT[12]=0.f; oT[13]=0.f; oT[14]=0.f; oT[15]=1.f;
      double qw=0.5*sqrt(fmax(1e-12, 1.0+R00+R11+R22));
      double qx=0.5*sqrt(fmax(0.0, 1.0+R00-R11-R22));
      double qy=0.5*sqrt(fmax(0.0, 1.0-R00+R11-R22));
      double qz=0.5*sqrt(fmax(0.0, 1.0-R00-R11+R22));
      if (R21-R12<0.0) qx=-qx;
      if (R02-R20<0.0) qy=-qy;
      if (R10-R01<0.0) qz=-qz;
      float* oQ = out + 128 + b*4;
      oQ[0]=(float)qw; oQ[1]=(float)qx; oQ[2]=(float)qy; oQ[3]=(float)qz;
      float* ot3 = out + 160 + b*3;
      ot3[0]=(float)F[0][3]; ot3[1]=(float)F[1][3]; ot3[2]=(float)F[2][3];
    }
  }
}

extern "C" void kernel_launch(void* const* d_in, const int* in_sizes, int n_in,
                              void* d_out, int out_size, void* d_ws, size_t ws_size,
                              hipStream_t stream) {
  const float* pc1 = (const float*)d_in[0];
  const float* pc2 = (const float*)d_in[1];
  float* out  = (float*)d_out;
  float* ws   = (float*)d_ws;

  // floats: partM 524,288 | partV 2,097,152 | rowdat 131,072 | ctr 128 uints
  // total = 11,010,560 B (<= proven 11,016,704 B)
  float*        partM  = ws;
  float4*       partV  = (float4*)(ws + 524288);
  float4*       rowdat = (float4*)(ws + 524288 + 2097152);
  unsigned int* ctr    = (unsigned int*)(ws + 524288 + 2097152 + 131072);

  hipMemsetAsync((void*)ctr, 0, 128*sizeof(unsigned int), stream);
  hipLaunchKernelGGL(k_soft, dim3(2048), dim3(256),  0, stream,
                     pc1, pc2, partM, partV, rowdat, ctr);
  hipLaunchKernelGGL(k_fin,  dim3(8),    dim3(1024), 0, stream,
                     pc1, rowdat, out);
}

// Round 11
// 146.450 us; speedup vs baseline: 2.4506x; 2.4506x over previous
//
#include <hip/hip_runtime.h>
#include <math.h>

#define NPTS 4096
#define EPSC 1e-5f
#define F2C (2.0f*1.44269504088896340736f)

#if __has_builtin(__builtin_amdgcn_exp2f)
#define FEXP2 __builtin_amdgcn_exp2f
#else
#define FEXP2(x) __expf((x)*0.6931471805599453f)
#endif

#define IDX(i,j) ((i)*((i)+1)/2 + (j))   // packed lower-tri, i>=j

typedef float f2 __attribute__((ext_vector_type(2)));
__device__ __forceinline__ f2 splat2(float v){ f2 r; r.x=v; r.y=v; return r; }

// one thread = one pc1 row; one block = (sample, 256-row block, 256-col chunk)
// pc2 chunk staged in LDS as SoA (x[],y[],z[],|p|^2[]); ONLINE softmax processing
// COLUMN PAIRS with packed fp32 (v_pk_fma_f32 path via ext_vector_type(2)).
__global__ void __launch_bounds__(256) k_soft(const float* __restrict__ pc1,
                                              const float* __restrict__ pc2,
                                              float* __restrict__ part){
  constexpr int CHN = 256, NC = 16;
  int bid = blockIdx.x;                          // 2048 blocks
  int chunk = bid & (NC-1), rb = (bid/NC) & 15, b = bid/(NC*16);

  __shared__ float xs[CHN], ys[CHN], zs[CHN], ws[CHN];   // 4KB SoA
  {
    const float* p2 = pc2 + (size_t)b*4*NPTS + chunk*CHN;
    for (int m = threadIdx.x; m < CHN; m += 256){
      float x = p2[m], y = p2[m+NPTS], z = p2[m+2*NPTS];
      xs[m]=x; ys[m]=y; zs[m]=z; ws[m]=x*x+y*y+z*z;
    }
  }
  __syncthreads();

  int n = rb*256 + threadIdx.x;
  const float* p1 = pc1 + (size_t)b*4*NPTS + n;
  float x1 = p1[0], y1 = p1[NPTS], z1 = p1[2*NPTS];
  float q1 = x1*x1 + y1*y1 + z1*z1;
  f2 mx = splat2(-2.f*x1), my = splat2(-2.f*y1), mz = splat2(-2.f*z1);
  f2 q12 = splat2(q1), eps2 = splat2(EPSC);

  // peel pair 0: init running max from both columns, accumulate normally
  f2 cx = *(const f2*)&xs[0], cy = *(const f2*)&ys[0];
  f2 cz = *(const f2*)&zs[0], cw = *(const f2*)&ws[0];
  f2 d = cw + q12;
  d = __builtin_elementwise_fma(mz, cz, d);
  d = __builtin_elementwise_fma(my, cy, d);
  d = __builtin_elementwise_fma(mx, cx, d);
  d = __builtin_elementwise_max(d, eps2);
  f2 r; r.x = __builtin_amdgcn_rcpf(d.x); r.y = __builtin_amdgcn_rcpf(d.y);
  f2 s = splat2(F2C) * r;
  float m_ = fmaxf(s.x, s.y);                    // running max (log2 units)
  f2 t = s - splat2(m_);
  f2 pe; pe.x = FEXP2(t.x); pe.y = FEXP2(t.y);
  f2 L2 = pe;
  f2 Ax2 = pe*cx, Ay2 = pe*cy, Az2 = pe*cz;

  #pragma unroll 8
  for (int p=1; p<CHN/2; ++p){
    cx = *(const f2*)&xs[2*p]; cy = *(const f2*)&ys[2*p];
    cz = *(const f2*)&zs[2*p]; cw = *(const f2*)&ws[2*p];
    d = cw + q12;
    d = __builtin_elementwise_fma(mz, cz, d);
    d = __builtin_elementwise_fma(my, cy, d);
    d = __builtin_elementwise_fma(mx, cx, d);
    d = __builtin_elementwise_max(d, eps2);
    r.x = __builtin_amdgcn_rcpf(d.x); r.y = __builtin_amdgcn_rcpf(d.y);
    t = __builtin_elementwise_fma(splat2(F2C), r, splat2(-m_));   // s - m
    float tmax = fmaxf(t.x, t.y);
    if (__any(tmax > 0.f)){                      // wave-uniform rescale (rare)
      float tp = fmaxf(tmax, 0.f);
      float sc = FEXP2(-tp);
      L2 *= sc; Ax2 *= sc; Ay2 *= sc; Az2 *= sc;
      m_ += tp;
      t = t - splat2(tp);                        // s - m_new
    }
    pe.x = FEXP2(t.x); pe.y = FEXP2(t.y);
    L2 += pe;
    Ax2 = __builtin_elementwise_fma(pe, cx, Ax2);
    Ay2 = __builtin_elementwise_fma(pe, cy, Ay2);
    Az2 = __builtin_elementwise_fma(pe, cz, Az2);
  }
  // fold pair lanes (same m_ for both)
  float L  = L2.x + L2.y;
  float Ax = Ax2.x + Ax2.y;
  float Ay = Ay2.x + Ay2.y;
  float Az = Az2.x + Az2.y;

  float* pp = part + ((size_t)(b*NC + chunk)*5)*NPTS + n;
  pp[0]=m_; pp[NPTS]=L; pp[2*NPTS]=Ax; pp[3*NPTS]=Ay; pp[4*NPTS]=Az;
}

// merge chunk partials -> pc_nearest + dist; per-block partial stats sums.
// 512 threads: two 256-thread halves each merge NC/2 chunks, combine via LDS.
template<int NC>
__global__ void __launch_bounds__(512) k_merge(const float* __restrict__ pc1,
                                               const float* __restrict__ part,
                                               float* __restrict__ pcn,
                                               float* __restrict__ dist,
                                               float* __restrict__ psum13){
  int b = blockIdx.x >> 4, rb = blockIdx.x & 15;                    // 128 blocks
  int t = threadIdx.x & 255, half = threadIdx.x >> 8;
  int n = rb*256 + t;
  constexpr int H = NC/2;
  float sc[H], Lc[H], Axc[H], Ayc[H], Azc[H];
  float S = -3.4e38f;
  #pragma unroll
  for (int c=0;c<H;c++){
    const float* pp = part + ((size_t)(b*NC + half*H + c)*5)*NPTS + n;
    sc[c]=pp[0]; Lc[c]=pp[NPTS]; Axc[c]=pp[2*NPTS]; Ayc[c]=pp[3*NPTS]; Azc[c]=pp[4*NPTS];
    S = fmaxf(S, sc[c]);
  }
  float L=0.f, Ax=0.f, Ay=0.f, Az=0.f;
  #pragma unroll
  for (int c=0;c<H;c++){
    float w = FEXP2(sc[c]-S);
    L=fmaf(w,Lc[c],L); Ax=fmaf(w,Axc[c],Ax); Ay=fmaf(w,Ayc[c],Ay); Az=fmaf(w,Azc[c],Az);
  }
  __shared__ float ex[256][5];
  if (half==1){ ex[t][0]=S; ex[t][1]=L; ex[t][2]=Ax; ex[t][3]=Ay; ex[t][4]=Az; }
  __syncthreads();
  __shared__ float red[4][13];
  if (half==0){
    float S1=ex[t][0];
    float M = fmaxf(S,S1);
    float w0=FEXP2(S-M), w1=FEXP2(S1-M);
    L = w0*L + w1*ex[t][1];
    Ax = w0*Ax + w1*ex[t][2];
    Ay = w0*Ay + w1*ex[t][3];
    Az = w0*Az + w1*ex[t][4];
    float inv = 1.f/L;
    float px=Ax*inv, py=Ay*inv, pz=Az*inv;
    const float* p1 = pc1 + (size_t)b*4*NPTS + n;
    float x1=p1[0], y1=p1[NPTS], z1=p1[2*NPTS];
    float dx=x1-px, dy=y1-py, dz=z1-pz;
    float dd=sqrtf(dx*dx+dy*dy+dz*dz);
    pcn[(size_t)(b*3+0)*NPTS+n]=px;
    pcn[(size_t)(b*3+1)*NPTS+n]=py;
    pcn[(size_t)(b*3+2)*NPTS+n]=pz;
    dist[(size_t)b*NPTS+n]=dd;
    float acc[13]={x1,y1,z1,x1*x1,y1*y1,z1*z1,px,py,pz,px*px,py*py,pz*pz,dd};
    int lane = t & 63, wv = t >> 6;
    #pragma unroll
    for (int k=0;k<13;k++){
      float v = acc[k];
      v += __shfl_xor(v,32); v += __shfl_xor(v,16); v += __shfl_xor(v,8);
      v += __shfl_xor(v,4);  v += __shfl_xor(v,2);  v += __shfl_xor(v,1);
      if (lane==0) red[wv][k]=v;
    }
  }
  __syncthreads();
  if (threadIdx.x<13)
    psum13[(size_t)blockIdx.x*13 + threadIdx.x] =
      red[0][threadIdx.x]+red[1][threadIdx.x]+red[2][threadIdx.x]+red[3][threadIdx.x];
}

__device__ __forceinline__ float elemA(const float* S, int i, int k){
  int bi=i>>2, bj=k>>2;
  int ii=i&3, jj=k&3;
  int lo = ii<jj?ii:jj, hi = ii<jj?jj:ii;
  int pe = 4*lo - ((lo*(lo-1))>>1) + (hi-lo);        // sym 4x4 -> 10 idx
  int w;
  if (bi==bj) w = (bi==2)?30:0;
  else {
    int blo = bi<bj?bi:bj, bhi = bi<bj?bj:bi;
    if (blo==0 && bhi==1) return 0.f;                // A01 block is zero
    w = (blo==0)?10:20;                              // (0,2)->wB, (1,2)->wC
  }
  return S[w+pe];
}

// fused per-sample: stats -> M^T M accumulation -> register inverse-power eigensolve -> compose
__global__ void __launch_bounds__(256) k_solve(const float* __restrict__ pc1,
                                               const float* __restrict__ pcn,
                                               const float* __restrict__ dist,
                                               const float* __restrict__ psum13,
                                               float* __restrict__ out){
  int b=blockIdx.x, t=threadIdx.x;                   // 8 blocks x 4 waves
  __shared__ float stot[13];
  __shared__ float sst[13];
  if (t<13){
    float s=0.f;
    #pragma unroll
    for (int i=0;i<16;i++) s += psum13[(size_t)(b*16+i)*13 + t];
    stot[t]=s;
  }
  __syncthreads();
  if (t==0){
    const float Nf = 4096.f, Nm1 = 4095.f;
    #pragma unroll
    for (int j=0;j<3;j++){
      float m  = stot[j]/Nf;
      float v  = (stot[3+j]-Nf*m*m)/Nm1;             // ddof=1
      sst[j]=m; sst[3+j]=sqrtf(fmaxf(v,0.f));
      float m2 = stot[6+j]/Nf;
      float v2 = (stot[9+j]-Nf*m2*m2)/Nm1;
      sst[6+j]=m2; sst[9+j]=sqrtf(fmaxf(v2,0.f));
    }
    sst[12]=stot[12]/Nf;
  }
  __syncthreads();
  float i1x=1.f/sst[3], i1y=1.f/sst[4], i1z=1.f/sst[5];
  float t1x=-sst[0]/sst[3], t1y=-sst[1]/sst[4], t1z=-sst[2]/sst[5];
  float i2x=1.f/sst[9], i2y=1.f/sst[10], i2z=1.f/sst[11];
  float t2x=-sst[6]/sst[9], t2y=-sst[7]/sst[10], t2z=-sst[8]/sst[11];
  float meanD=sst[12];

  float acc[40];
  #pragma unroll
  for (int k=0;k<40;k++) acc[k]=0.f;
  #pragma unroll 4
  for (int i=0;i<16;i++){
    int n=i*256+t;
    const float* p1 = pc1 + (size_t)b*4*NPTS + n;
    float X1=fmaf(p1[0],i1x,t1x), Y1=fmaf(p1[NPTS],i1y,t1y), Z1=fmaf(p1[2*NPTS],i1z,t1z);
    float X2=fmaf(pcn[(size_t)(b*3+0)*NPTS+n],i2x,t2x);
    float Y2=fmaf(pcn[(size_t)(b*3+1)*NPTS+n],i2y,t2y);
    float Z2=fmaf(pcn[(size_t)(b*3+2)*NPTS+n],i2z,t2z);
    // sigmoid((dist-mean-EPS)*-1e10) > 0.5  <=>  (dist-mean)-EPS < 0
    float zthr = (dist[(size_t)b*NPTS+n] - meanD) - EPSC;
    float msk = (zthr < 0.f) ? 1.f : 0.f;
    float tz = msk*Z2;
    float wA = tz*Z2, wB = -tz*X2, wC = -tz*Y2;
    float wD = msk*fmaf(X2,X2,Y2*Y2);
    float ee[10]={X1*X1, X1*Y1, X1*Z1, X1, Y1*Y1, Y1*Z1, Y1, Z1*Z1, Z1, 1.f};
    #pragma unroll
    for (int j=0;j<10;j++){
      acc[j]    = fmaf(wA,ee[j],acc[j]);
      acc[10+j] = fmaf(wB,ee[j],acc[10+j]);
      acc[20+j] = fmaf(wC,ee[j],acc[20+j]);
      acc[30+j] = fmaf(wD,ee[j],acc[30+j]);
    }
  }
  __shared__ float red[4][40];
  __shared__ float SS[40];
  {
    int lane=t&63, wv=t>>6;
    #pragma unroll
    for (int k=0;k<40;k++){
      float v=acc[k];
      v+=__shfl_xor(v,32); v+=__shfl_xor(v,16); v+=__shfl_xor(v,8);
      v+=__shfl_xor(v,4);  v+=__shfl_xor(v,2);  v+=__shfl_xor(v,1);
      if(lane==0) red[wv][k]=v;
    }
  }
  __syncthreads();
  if (t<40) SS[t]=red[0][t]+red[1][t]+red[2][t]+red[3][t];
  __syncthreads();

  if (t<64){
    // ---- register-resident inverse-power eigensolve (wave 0) ----
    float a[78];
    #pragma unroll
    for (int i=0;i<12;i++)
      #pragma unroll
      for (int j=0;j<=i;j++)
        a[IDX(i,j)] = elemA(SS,i,j);
    {
      float tr=0.f;
      #pragma unroll
      for (int i=0;i<12;i++) tr += a[IDX(i,i)];
      float eps = 1e-5f * tr * (1.f/12.f);           // uniform shift: eigvecs unchanged
      #pragma unroll
      for (int i=0;i<12;i++) a[IDX(i,i)] += eps;
    }
    #pragma unroll
    for (int j=0;j<12;j++){
      float s = a[IDX(j,j)];
      #pragma unroll
      for (int k=0;k<j;k++) s = fmaf(-a[IDX(j,k)], a[IDX(j,k)], s);
      float d = sqrtf(fmaxf(s, 1e-30f));
      a[IDX(j,j)] = d;
      float dinv = __builtin_amdgcn_rcpf(d);
      #pragma unroll
      for (int i=j+1;i<12;i++){
        float s2 = a[IDX(i,j)];
        #pragma unroll
        for (int k=0;k<j;k++) s2 = fmaf(-a[IDX(i,k)], a[IDX(j,k)], s2);
        a[IDX(i,j)] = s2 * dinv;
      }
    }
    float y[12], Brow[12];
    #pragma unroll
    for (int i=0;i<12;i++){
      float s = (i==t) ? 1.f : 0.f;
      #pragma unroll
      for (int k=0;k<i;k++) s = fmaf(-a[IDX(i,k)], y[k], s);
      y[i] = s * __builtin_amdgcn_rcpf(a[IDX(i,i)]);
    }
    #pragma unroll
    for (int i=11;i>=0;i--){
      float s = y[i];
      #pragma unroll
      for (int k=11;k>i;k--) s = fmaf(-a[IDX(k,i)], Brow[k], s);
      Brow[i] = s * __builtin_amdgcn_rcpf(a[IDX(i,i)]);
    }
    {
      float mxv = 0.f;
      #pragma unroll
      for (int i=0;i<12;i++) mxv = fmaxf(mxv, fabsf(Brow[i]));
      mxv = fmaxf(mxv, __shfl_xor(mxv,1)); mxv = fmaxf(mxv, __shfl_xor(mxv,2));
      mxv = fmaxf(mxv, __shfl_xor(mxv,4)); mxv = fmaxf(mxv, __shfl_xor(mxv,8));
      float sc = __builtin_amdgcn_rcpf(mxv);
      #pragma unroll
      for (int i=0;i<12;i++) Brow[i] *= sc;
    }
    #pragma unroll
    for (int rep=0; rep<2; ++rep){                   // B -> B^2 -> B^4
      float nr[12];
      #pragma unroll
      for (int i=0;i<12;i++) nr[i]=0.f;
      #pragma unroll
      for (int k=0;k<12;k++){
        float bjk = Brow[k];
        #pragma unroll
        for (int m2=0;m2<12;m2++){
          float bkm = __shfl(Brow[m2], k);
          nr[m2] = fmaf(bjk, bkm, nr[m2]);
        }
      }
      float mxv = 0.f;
      #pragma unroll
      for (int i=0;i<12;i++) mxv = fmaxf(mxv, fabsf(nr[i]));
      mxv = fmaxf(mxv, __shfl_xor(mxv,1)); mxv = fmaxf(mxv, __shfl_xor(mxv,2));
      mxv = fmaxf(mxv, __shfl_xor(mxv,4)); mxv = fmaxf(mxv, __shfl_xor(mxv,8));
      float sc = __builtin_amdgcn_rcpf(mxv);
      #pragma unroll
      for (int i=0;i<12;i++) Brow[i] = nr[i]*sc;
    }
    float v = 0.f;
    #pragma unroll
    for (int i=0;i<12;i++) v += Brow[i];
    #pragma unroll
    for (int it=0; it<14; ++it){
      float w = 0.f;
      #pragma unroll
      for (int k=0;k<12;k++) w = fmaf(Brow[k], __shfl(v,k), w);
      float nn = w*w;
      nn += __shfl_xor(nn,1); nn += __shfl_xor(nn,2);
      nn += __shfl_xor(nn,4); nn += __shfl_xor(nn,8);
      v = w * rsqrtf(nn);
    }
    float pvf[12];
    #pragma unroll
    for (int i=0;i<12;i++) pvf[i] = __shfl(v, i);

    if (t==0){
      double pv[12];
      #pragma unroll
      for (int i=0;i<12;i++) pv[i]=(double)pvf[i];
      if (pv[10]<0.0){
        #pragma unroll
        for (int i=0;i<12;i++) pv[i]=-pv[i];
      }
      double nrm = sqrt(pv[8]*pv[8]+pv[9]*pv[9]+pv[10]*pv[10]);
      #pragma unroll
      for (int i=0;i<12;i++) pv[i]/=nrm;
      double m1[3]={sst[0],sst[1],sst[2]}, sd1[3]={sst[3],sst[4],sst[5]};
      double m2[3]={sst[6],sst[7],sst[8]}, sd2[3]={sst[9],sst[10],sst[11]};
      double Td[3][4]={{pv[0],pv[1],pv[2],pv[3]},
                       {pv[4],pv[5],pv[6],pv[7]},
                       {pv[8],pv[9],pv[10],pv[11]}};
      double F[3][4];
      for (int i=0;i<3;i++){
        double b3 = Td[i][3];
        for (int j=0;j<3;j++){
          F[i][j] = sd2[i]*(Td[i][j]/sd1[j]);        // inv(T2) @ Tdlt @ T1
          b3 += Td[i][j]*(-m1[j]/sd1[j]);
        }
        F[i][3] = sd2[i]*b3 + m2[i];
      }
      double zx=F[0][2],zy=F[1][2],zz2=F[2][2];
      double zn=sqrt(zx*zx+zy*zy+zz2*zz2);
      zx/=zn; zy/=zn; zz2/=zn;
      double yx=F[0][1],yy=F[1][1],yz=F[2][1];
      double xx=yy*zz2-yz*zy, xy=yz*zx-yx*zz2, xz=yx*zy-yy*zx;
      double xn=sqrt(xx*xx+xy*xy+xz*xz);
      xx/=xn; xy/=xn; xz/=xn;
      double y2x=zy*xz-zz2*xy, y2y=zz2*xx-zx*xz, y2z=zx*xy-zy*xx;
      double R00=xx,R01=y2x,R02=zx;
      double R10=xy,R11=y2y,R12=zy;
      double R20=xz,R21=y2z,R22=zz2;
      float* oT = out + b*16;
      oT[0]=(float)R00; oT[1]=(float)R01; oT[2]=(float)R02; oT[3]=(float)F[0][3];
      oT[4]=(float)R10; oT[5]=(float)R11; oT[6]=(float)R12; oT[7]=(float)F[1][3];
      oT[8]=(float)R20; oT[9]=(float)R21; oT[10]=(float)R22; oT[11]=(float)F[2][3];
      oT[12]=0.f; oT[13]=0.f; oT[14]=0.f; oT[15]=1.f;
      double qw=0.5*sqrt(fmax(1e-12, 1.0+R00+R11+R22));
      double qx=0.5*sqrt(fmax(0.0, 1.0+R00-R11-R22));
      double qy=0.5*sqrt(fmax(0.0, 1.0-R00+R11-R22));
      double qz=0.5*sqrt(fmax(0.0, 1.0-R00-R11+R22));
      if (R21-R12<0.0) qx=-qx;
      if (R02-R20<0.0) qy=-qy;
      if (R10-R01<0.0) qz=-qz;
      float* oQ = out + 128 + b*4;
      oQ[0]=(float)qw; oQ[1]=(float)qx; oQ[2]=(float)qy; oQ[3]=(float)qz;
      float* ot3 = out + 160 + b*3;
      ot3[0]=(float)F[0][3]; ot3[1]=(float)F[1][3]; ot3[2]=(float)F[2][3];
    }
  }
}

extern "C" void kernel_launch(void* const* d_in, const int* in_sizes, int n_in,
                              void* d_out, int out_size, void* d_ws, size_t ws_size,
                              hipStream_t stream) {
  const float* pc1 = (const float*)d_in[0];
  const float* pc2 = (const float*)d_in[1];
  float* out  = (float*)d_out;
  float* ws   = (float*)d_ws;

  // floats: part 8*16*5*4096 = 2,621,440 | pcn 98,304 | dist 32,768 | psum13 1,664
  // total 2,754,176 floats = 11,016,704 B (proven fits, round 3)
  float* part  = ws;
  float* pcn   = part + 2621440;
  float* dist  = pcn + 98304;
  float* psum13= dist + 32768;

  hipLaunchKernelGGL(k_soft,      dim3(2048), dim3(256), 0, stream, pc1, pc2, part);
  hipLaunchKernelGGL(k_merge<16>, dim3(128),  dim3(512), 0, stream, pc1, part, pcn, dist, psum13);
  hipLaunchKernelGGL(k_solve,     dim3(8),    dim3(256), 0, stream, pc1, pcn, dist, psum13, out);
}